// Round 3
// baseline (471.484 us; speedup 1.0000x reference)
//
#include <hip/hip_runtime.h>

// SALSA3D: C=64, Ci=16, D=8, H=W=160, K=3, S=2, P=1 -> nH=nW=80, L=6400, F=144
// proj(bf16) -> unfold(Q/K row-major, V^T f-major) -> MFMA flash attn
// (S^T=K@Q^T, ksplit=5, k-tile 32, 2-wave blocks) -> merge -> fold+final fused
//
// ws layout (f32 offsets), lifetime overlays:
//   PatQK bf16 [2][2][6400][144]   f[0         .. 1,843,200)  dead after attn
//   VT    bf16 [2][144][6400]      f[1,843,200 .. 2,764,800)
//   ml    f32  [2][5][6400]x2      f[2,764,800 .. 2,892,800)
//   P3    bf16 [2][48][25600]      f[2,892,800 .. 4,121,600)  dead after unfold
//   Opart bf16 [2][5][6400][144]   f[2,892,800 .. 7,500,800)  overlays P3
//   Zi    f32  [2][6400][144]      f[0 .. 1,843,200)          overlays PatQK
// high-water 7,500,800 f32 = 30.0 MB

#define NPIX 25600
#define LOG2E10 14.42695040888963f  // 10 * log2(e): softmax scale folded into exp2

typedef float floatx16 __attribute__((ext_vector_type(16)));
typedef short short8 __attribute__((ext_vector_type(8)));

__device__ inline unsigned short f2bf(float x) {
    union { float f; unsigned int u; } v; v.f = x;
    unsigned int r = v.u + 0x7fffu + ((v.u >> 16) & 1u);
    return (unsigned short)(r >> 16);
}
__device__ inline float bf2f(unsigned short u) {
    union { unsigned int u; float f; } v; v.u = ((unsigned int)u) << 16;
    return v.f;
}

// ---------------- K1: 1x1x1 conv projections at mid depth (bf16 out) ----------------
__global__ void k_proj(const float* __restrict__ b,
                       const float* __restrict__ gw, const float* __restrict__ gb,
                       const float* __restrict__ thw, const float* __restrict__ thb,
                       const float* __restrict__ phw, const float* __restrict__ phb,
                       unsigned short* __restrict__ P3) {
    __shared__ float Wl[3 * 1024];
    __shared__ float Bl[48];
    int tid = threadIdx.x;
    int g = blockIdx.y;
    int pix = blockIdx.x * 256 + tid;
    for (int i = tid; i < 1024; i += 256) {
        Wl[i]        = gw[i];   // s=0: query source (g_w)
        Wl[1024 + i] = phw[i];  // s=1: key source   (phi_w)
        Wl[2048 + i] = thw[i];  // s=2: value source (theta_w)
    }
    if (tid < 16) { Bl[tid] = gb[tid]; Bl[16 + tid] = phb[tid]; Bl[32 + tid] = thb[tid]; }
    __syncthreads();

    float acc[48];
#pragma unroll
    for (int o = 0; o < 48; o++) acc[o] = 0.f;
    const float* bp = b + (size_t)g * 64 * 8 * NPIX + (size_t)4 * NPIX + pix;
    for (int c = 0; c < 64; c++) {
        float xv = bp[(size_t)c * 8 * NPIX];
#pragma unroll
        for (int o = 0; o < 48; o++)
            acc[o] += Wl[(o >> 4) * 1024 + (o & 15) * 64 + c] * xv;
    }
#pragma unroll
    for (int o = 0; o < 48; o++)
        P3[(size_t)(g * 48 + o) * NPIX + pix] = f2bf(acc[o] + Bl[o]);
}

// ---------------- K2: unfold Q,K row-major + V transposed (one kernel) ----------------
__global__ void k_unfold(const unsigned short* __restrict__ P3,
                         unsigned short* __restrict__ PatQK,
                         unsigned short* __restrict__ VT) {
    int idx = blockIdx.x * 256 + threadIdx.x;  // 5,529,600 = 21600*256 exact
    if (idx < 3686400) {                       // [g][s][l][f] -> PatQK
        int f = idx % 144;
        int l = (idx / 144) % 6400;
        int s = (idx / 921600) & 1;
        int g = idx / 1843200;
        int ci = f / 9, kr = (f % 9) / 3, kc = f % 3;
        int oh = l / 80, ow = l % 80;
        int h = oh * 2 + kr - 1, w = ow * 2 + kc - 1;
        unsigned short v = 0;
        if (h >= 0 && h < 160 && w >= 0 && w < 160)
            v = P3[(size_t)(g * 48 + s * 16 + ci) * NPIX + h * 160 + w];
        PatQK[idx] = v;
    } else {                                   // [g][f][l] -> VT
        int j = idx - 3686400;
        int l = j % 6400;
        int f = (j / 6400) % 144;
        int g = j / 921600;
        int ci = f / 9, kr = (f % 9) / 3, kc = f % 3;
        int oh = l / 80, ow = l % 80;
        int h = oh * 2 + kr - 1, w = ow * 2 + kc - 1;
        unsigned short v = 0;
        if (h >= 0 && h < 160 && w >= 0 && w < 160)
            v = P3[(size_t)(g * 48 + 32 + ci) * NPIX + h * 160 + w];
        VT[j] = v;
    }
}

// ---------------- K3: MFMA flash attention (S^T = K@Q^T) ----------------
// 2 waves/block, 64 queries/block, ksplit=5 (1280 keys), k-tile 32, 40 iters.
__global__ __launch_bounds__(128, 2) void k_attn(
    const unsigned short* __restrict__ PatQK, const unsigned short* __restrict__ VT,
    float* __restrict__ ml, unsigned short* __restrict__ Opart) {
    __shared__ unsigned short Ks[32 * 152];    // K tile, rows padded 144->152
    __shared__ unsigned short Vs[160 * 40];    // V^T tile, rows padded 32->40 (144..159 scratch)
    __shared__ unsigned short Pl[2 * 32 * 40]; // per-wave P^T [q][k], rows padded

    int tid = threadIdx.x;
    int lane = tid & 63;
    int w = tid >> 6;
    int l31 = lane & 31;
    int h5 = lane >> 5;
    int split = blockIdx.y, g = blockIdx.z;
    int q = blockIdx.x * 64 + w * 32 + l31;

    const unsigned short* Qg = PatQK + ((size_t)g * 2 + 0) * 6400 * 144;
    const unsigned short* Kg = PatQK + ((size_t)g * 2 + 1) * 6400 * 144 + (size_t)split * 1280 * 144;
    const unsigned short* Vg = VT + (size_t)g * 144 * 6400 + split * 1280;

    // Q fragments (B operand) pinned in registers
    short8 qf[9];
#pragma unroll
    for (int fs = 0; fs < 9; fs++)
        qf[fs] = *(const short8*)(Qg + (size_t)q * 144 + fs * 16 + h5 * 8);

    floatx16 O[5];
#pragma unroll
    for (int i = 0; i < 5; i++) O[i] = (floatx16)0.f;
    float m = -1e30f, lsum = 0.f;

    unsigned short* Plw = Pl + w * (32 * 40);

    for (int it = 0; it < 40; it++) {
        __syncthreads();
        const unsigned short* Kt = Kg + it * 32 * 144;
        const unsigned short* Vtile = Vg + it * 32;
        // stage K (32x144) + V^T (144x32), 1152 short8 over 128 threads
        for (int c = tid; c < 1152; c += 128) {
            if (c < 576) {
                int row = c / 18, col = c - row * 18;
                *(short8*)&Ks[row * 152 + col * 8] = *(const short8*)(Kt + row * 144 + col * 8);
            } else {
                int vv = c - 576;
                int f = vv >> 2, colg = vv & 3;
                *(short8*)&Vs[f * 40 + colg * 8] = *(const short8*)(Vtile + (size_t)f * 6400 + colg * 8);
            }
        }
        __syncthreads();

        // S^T: one 32x32 C tile, reduce f=144 in 9 MFMA steps
        floatx16 S0 = (floatx16)0.f;
#pragma unroll
        for (int fs = 0; fs < 9; fs++) {
            short8 a0 = *(const short8*)&Ks[l31 * 152 + fs * 16 + h5 * 8];
            S0 = __builtin_amdgcn_mfma_f32_32x32x16_bf16(a0, qf[fs], S0, 0, 0, 0);
        }

        // online softmax (lane's 16 scores all belong to query col=l31)
        float mt = -1e30f;
#pragma unroll
        for (int r = 0; r < 16; r++) mt = fmaxf(mt, S0[r]);
        mt = fmaxf(mt, __shfl_xor(mt, 32, 64));
        float mnew = fmaxf(m, mt);
        float alpha = exp2f(LOG2E10 * (m - mnew));
        float ps = 0.f;
        float p0[16];
#pragma unroll
        for (int r = 0; r < 16; r++) {
            p0[r] = exp2f(LOG2E10 * (S0[r] - mnew));
            ps += p0[r];
        }
        ps += __shfl_xor(ps, 32, 64);
        lsum = lsum * alpha + ps;
        m = mnew;
        if (__any(alpha < 1.f)) {
#pragma unroll
            for (int t5 = 0; t5 < 5; t5++)
#pragma unroll
                for (int r = 0; r < 16; r++) O[t5][r] *= alpha;
        }

        // P^T -> per-wave LDS [q][k] (C rows: k = rg*8 + h5*4 + rr)
#pragma unroll
        for (int rg = 0; rg < 4; rg++) {
            ushort4 w0;
            w0.x = f2bf(p0[4 * rg + 0]); w0.y = f2bf(p0[4 * rg + 1]);
            w0.z = f2bf(p0[4 * rg + 2]); w0.w = f2bf(p0[4 * rg + 3]);
            *(ushort4*)&Plw[l31 * 40 + rg * 8 + h5 * 4] = w0;
        }

        // O^T += V^T @ P^T (A rows 144..159 are scratch -> discarded C rows)
#pragma unroll
        for (int ks = 0; ks < 2; ks++) {
            short8 pb = *(const short8*)&Plw[l31 * 40 + ks * 16 + h5 * 8];
#pragma unroll
            for (int ft = 0; ft < 5; ft++) {
                short8 va = *(const short8*)&Vs[(ft * 32 + l31) * 40 + ks * 16 + h5 * 8];
                O[ft] = __builtin_amdgcn_mfma_f32_32x32x16_bf16(va, pb, O[ft], 0, 0, 0);
            }
        }
    }

    if (h5 == 0)
        ((float2*)ml)[((size_t)g * 5 + split) * 6400 + q] = make_float2(m, lsum);

    unsigned short* Og = Opart + (((size_t)(g * 5 + split)) * 6400 + q) * 144;
#pragma unroll
    for (int ft = 0; ft < 5; ft++)
#pragma unroll
        for (int rg = 0; rg < 4; rg++) {
            int f = ft * 32 + rg * 8 + h5 * 4;
            if (f < 144) {
                ushort4 st;
                st.x = f2bf(O[ft][4 * rg + 0]); st.y = f2bf(O[ft][4 * rg + 1]);
                st.z = f2bf(O[ft][4 * rg + 2]); st.w = f2bf(O[ft][4 * rg + 3]);
                *(ushort4*)(Og + f) = st;
            }
        }
}

// ---------------- K3b: merge ksplit partials ----------------
__global__ void k_merge(const float* __restrict__ mlp, const unsigned short* __restrict__ Opart,
                        float* __restrict__ Zi) {
    int idx = blockIdx.x * 256 + threadIdx.x;  // 2*6400*36 exact
    int fg = idx % 36;
    int q = (idx / 36) % 6400;
    int g = idx / (36 * 6400);
    const float2* ml2 = (const float2*)mlp;
    float2 s[5];
#pragma unroll
    for (int k = 0; k < 5; k++) s[k] = ml2[((size_t)g * 5 + k) * 6400 + q];
    float ms = s[0].x;
#pragma unroll
    for (int k = 1; k < 5; k++) ms = fmaxf(ms, s[k].x);
    float wgt[5], denom = 0.f;
#pragma unroll
    for (int k = 0; k < 5; k++) {
        wgt[k] = exp2f(LOG2E10 * (s[k].x - ms));
        denom += wgt[k] * s[k].y;
    }
    float inv = 1.f / denom;
    float a0 = 0.f, a1 = 0.f, a2 = 0.f, a3 = 0.f;
#pragma unroll
    for (int k = 0; k < 5; k++) {
        ushort4 u = *(const ushort4*)(Opart + (((size_t)(g * 5 + k)) * 6400 + q) * 144 + fg * 4);
        a0 += wgt[k] * bf2f(u.x); a1 += wgt[k] * bf2f(u.y);
        a2 += wgt[k] * bf2f(u.z); a3 += wgt[k] * bf2f(u.w);
    }
    float4 out = make_float4(a0 * inv, a1 * inv, a2 * inv, a3 * inv);
    *(float4*)(Zi + ((size_t)g * 6400 + q) * 144 + fg * 4) = out;
}

// ---------------- K4: fused fold(overlap-add+norm) + conv1x1 + residual add ----------------
__global__ void k_foldfinal(const float* __restrict__ b, const float* __restrict__ Zi,
                            const float* __restrict__ Ww, const float* __restrict__ Wb,
                            float* __restrict__ out) {
    __shared__ float z[16 * 64];
    __shared__ float Wl[64 * 16];
    __shared__ float Bl[64];
    int tid = threadIdx.x;
    int g = blockIdx.y;
    int pxb = blockIdx.x * 64;
    for (int i = tid; i < 1024; i += 256) Wl[i] = Ww[i];
    if (tid < 64) Bl[tid] = Wb[tid];

    // fold phase: 1024 zi2 entries, 4 per thread
#pragma unroll
    for (int j = 0; j < 4; j++) {
        int e = tid + 256 * j;
        int ci = e >> 6, px = e & 63;
        int pix = pxb + px;
        int h = pix / 160, w = pix % 160;
        int ohs[2], krs[2], nh = 0;
#pragma unroll
        for (int kr = 0; kr < 3; kr++) {
            int t = h + 1 - kr;
            if (t >= 0 && (t & 1) == 0 && (t >> 1) < 80) { ohs[nh] = t >> 1; krs[nh] = kr; nh++; }
        }
        int ows[2], kcs[2], nw = 0;
#pragma unroll
        for (int kc = 0; kc < 3; kc++) {
            int t = w + 1 - kc;
            if (t >= 0 && (t & 1) == 0 && (t >> 1) < 80) { ows[nw] = t >> 1; kcs[nw] = kc; nw++; }
        }
        float sm = 0.f;
        for (int a = 0; a < nh; a++)
            for (int bb = 0; bb < nw; bb++) {
                int l = ohs[a] * 80 + ows[bb];
                int f = ci * 9 + krs[a] * 3 + kcs[bb];
                sm += Zi[((size_t)g * 6400 + l) * 144 + f];
            }
        z[ci * 64 + px] = sm / (float)(nh * nw);
    }
    __syncthreads();

    int px4 = tid & 15;
    int cg = tid >> 4;
    float acc[4][4];
#pragma unroll
    for (int c4 = 0; c4 < 4; c4++) {
        float bv = Bl[cg + 16 * c4];
#pragma unroll
        for (int j = 0; j < 4; j++) acc[c4][j] = bv;
    }
#pragma unroll
    for (int ci = 0; ci < 16; ci++) {
        float zv[4];
#pragma unroll
        for (int j = 0; j < 4; j++) zv[j] = z[ci * 64 + px4 * 4 + j];
#pragma unroll
        for (int c4 = 0; c4 < 4; c4++) {
            float wv = Wl[(cg + 16 * c4) * 16 + ci];
#pragma unroll
            for (int j = 0; j < 4; j++) acc[c4][j] += wv * zv[j];
        }
    }
    for (int d = 0; d < 8; d++) {
#pragma unroll
        for (int c4 = 0; c4 < 4; c4++) {
            int c = cg + 16 * c4;
            size_t base = ((size_t)(g * 64 + c) * 8 + d) * NPIX + pxb + px4 * 4;
            float4 bv = *(const float4*)(b + base);
            float4 ov = make_float4(bv.x + acc[c4][0], bv.y + acc[c4][1],
                                    bv.z + acc[c4][2], bv.w + acc[c4][3]);
            *(float4*)(out + base) = ov;
        }
    }
}

extern "C" void kernel_launch(void* const* d_in, const int* in_sizes, int n_in,
                              void* d_out, int out_size, void* d_ws, size_t ws_size,
                              hipStream_t stream) {
    const float* b   = (const float*)d_in[0];
    const float* gw  = (const float*)d_in[1];
    const float* gb  = (const float*)d_in[2];
    const float* thw = (const float*)d_in[3];
    const float* thb = (const float*)d_in[4];
    const float* phw = (const float*)d_in[5];
    const float* phb = (const float*)d_in[6];
    const float* Ww  = (const float*)d_in[7];
    const float* Wb  = (const float*)d_in[8];
    float* out = (float*)d_out;
    float* ws = (float*)d_ws;

    unsigned short* PatQK = (unsigned short*)ws;                 // 3,686,400 bf16
    unsigned short* VT    = (unsigned short*)(ws + 1843200);     // 1,843,200 bf16
    float*          ml    = ws + 2764800;                        //   128,000 f32
    unsigned short* P3    = (unsigned short*)(ws + 2892800);     // 2,457,600 bf16
    unsigned short* Opart = (unsigned short*)(ws + 2892800);     // 9,216,000 bf16 (overlays P3)
    float*          Zi    = ws;                                  // overlays PatQK

    k_proj<<<dim3(100, 2), 256, 0, stream>>>(b, gw, gb, thw, thb, phw, phb, P3);
    k_unfold<<<dim3(21600), 256, 0, stream>>>(P3, PatQK, VT);
    k_attn<<<dim3(100, 5, 2), 128, 0, stream>>>(PatQK, VT, ml, Opart);
    k_merge<<<dim3(1800), 256, 0, stream>>>(ml, Opart, Zi);
    k_foldfinal<<<dim3(400, 2), 256, 0, stream>>>(b, Zi, Ww, Wb, out);
}

// Round 4
// 468.733 us; speedup vs baseline: 1.0059x; 1.0059x over previous
//
#include <hip/hip_runtime.h>

// SALSA3D: C=64, Ci=16, D=8, H=W=160, K=3, S=2, P=1 -> nH=nW=80, L=6400, F=144
// proj(bf16) -> unfold -> MFMA flash attn (S^T=K@Q^T, async dbuf global_load_lds,
// shuffle-P, runtime ksplit) -> merge -> scatter-fold(atomic) -> final conv+add
//
// ws layout (f32 offsets), lifetime overlays:
//   PatQK bf16 [2][2][6400][144]   f[0         .. 1,843,200)  dead after attn
//   VT    bf16 [2][144][6400]      f[1,843,200 .. 2,764,800)  dead after attn
//   ml    f32  [2][ns][6400]x2     f[2,764,800 .. 2,969,600)  (sized for ns=8)
//   P3    bf16 [2][48][25600]      f[2,969,600 .. 4,198,400)  dead after unfold
//   Opart bf16 [2][ns][6400][144]  f[2,969,600 .. +ns*921600) overlays P3
//   Zi    f32  [2][6400][144]      f[0 .. 1,843,200)          overlays PatQK
//   zi2   f32  [2][16][25600]      f[1,843,200 .. 2,662,400)  overlays VT
// high-water: ns=8 -> 41.4 MB, ns=5 -> 30.3 MB (chosen from ws_size)

#define NPIX 25600
#define LOG2E10 14.42695040888963f  // 10 * log2(e): softmax scale folded into exp2

typedef float floatx16 __attribute__((ext_vector_type(16)));
typedef short short8 __attribute__((ext_vector_type(8)));

__device__ inline unsigned short f2bf(float x) {
    union { float f; unsigned int u; } v; v.f = x;
    unsigned int r = v.u + 0x7fffu + ((v.u >> 16) & 1u);
    return (unsigned short)(r >> 16);
}
__device__ inline float bf2f(unsigned short u) {
    union { unsigned int u; float f; } v; v.u = ((unsigned int)u) << 16;
    return v.f;
}
__device__ inline unsigned int pack2bf(float lo, float hi) {
    return (unsigned int)f2bf(lo) | ((unsigned int)f2bf(hi) << 16);
}
__device__ inline void gload16(const void* g, void* l) {
    __builtin_amdgcn_global_load_lds(
        (const __attribute__((address_space(1))) unsigned int*)g,
        (__attribute__((address_space(3))) unsigned int*)l, 16, 0, 0);
}

// ---------------- K1: 1x1x1 conv projections at mid depth (bf16 out) ----------------
__global__ void k_proj(const float* __restrict__ b,
                       const float* __restrict__ gw, const float* __restrict__ gb,
                       const float* __restrict__ thw, const float* __restrict__ thb,
                       const float* __restrict__ phw, const float* __restrict__ phb,
                       unsigned short* __restrict__ P3) {
    __shared__ float Wl[3 * 1024];
    __shared__ float Bl[48];
    int tid = threadIdx.x;
    int g = blockIdx.y;
    int pix = blockIdx.x * 256 + tid;
    for (int i = tid; i < 1024; i += 256) {
        Wl[i]        = gw[i];   // s=0: query source (g_w)
        Wl[1024 + i] = phw[i];  // s=1: key source   (phi_w)
        Wl[2048 + i] = thw[i];  // s=2: value source (theta_w)
    }
    if (tid < 16) { Bl[tid] = gb[tid]; Bl[16 + tid] = phb[tid]; Bl[32 + tid] = thb[tid]; }
    __syncthreads();

    float acc[48];
#pragma unroll
    for (int o = 0; o < 48; o++) acc[o] = 0.f;
    const float* bp = b + (size_t)g * 64 * 8 * NPIX + (size_t)4 * NPIX + pix;
    for (int c = 0; c < 64; c++) {
        float xv = bp[(size_t)c * 8 * NPIX];
#pragma unroll
        for (int o = 0; o < 48; o++)
            acc[o] += Wl[(o >> 4) * 1024 + (o & 15) * 64 + c] * xv;
    }
#pragma unroll
    for (int o = 0; o < 48; o++)
        P3[(size_t)(g * 48 + o) * NPIX + pix] = f2bf(acc[o] + Bl[o]);
}

// ---------------- K2: unfold Q,K row-major + V transposed ----------------
__global__ void k_unfold(const unsigned short* __restrict__ P3,
                         unsigned short* __restrict__ PatQK,
                         unsigned short* __restrict__ VT) {
    int idx = blockIdx.x * 256 + threadIdx.x;  // 5,529,600 = 21600*256 exact
    if (idx < 3686400) {                       // [g][s][l][f] -> PatQK
        int f = idx % 144;
        int l = (idx / 144) % 6400;
        int s = (idx / 921600) & 1;
        int g = idx / 1843200;
        int ci = f / 9, kr = (f % 9) / 3, kc = f % 3;
        int oh = l / 80, ow = l % 80;
        int h = oh * 2 + kr - 1, w = ow * 2 + kc - 1;
        unsigned short v = 0;
        if (h >= 0 && h < 160 && w >= 0 && w < 160)
            v = P3[(size_t)(g * 48 + s * 16 + ci) * NPIX + h * 160 + w];
        PatQK[idx] = v;
    } else {                                   // [g][f][l] -> VT
        int j = idx - 3686400;
        int l = j % 6400;
        int f = (j / 6400) % 144;
        int g = j / 921600;
        int ci = f / 9, kr = (f % 9) / 3, kc = f % 3;
        int oh = l / 80, ow = l % 80;
        int h = oh * 2 + kr - 1, w = ow * 2 + kc - 1;
        unsigned short v = 0;
        if (h >= 0 && h < 160 && w >= 0 && w < 160)
            v = P3[(size_t)(g * 48 + 32 + ci) * NPIX + h * 160 + w];
        VT[j] = v;
    }
}

// ---------------- K3: MFMA flash attention, async dbuf, shuffle-P ----------------
// 4 waves/block, 128 q/block (32 q/wave), k-tile 32, runtime ksplit.
// LDS in fragment-read order: chunk*1KB + lane*16B (global_load_lds layout).
__global__ __launch_bounds__(256, 3) void k_attn(
    const unsigned short* __restrict__ PatQK, const unsigned short* __restrict__ VT,
    float* __restrict__ ml, unsigned short* __restrict__ Opart,
    int nsplit, int niter, int klen) {
    __shared__ unsigned short Ks[2][9 * 512];   // K tile: 9 chunks (fs), lane=(h5*32+l31)
    __shared__ unsigned short Vs[2][10 * 512];  // V^T tile: 10 chunks (ft*2+ks)

    int tid = threadIdx.x;
    int lane = tid & 63;
    int w = tid >> 6;
    int l31 = lane & 31, h5 = lane >> 5;
    int split = blockIdx.y, g = blockIdx.z;
    int q = blockIdx.x * 128 + w * 32 + l31;

    const unsigned short* Qg = PatQK + (size_t)g * 2 * 921600;
    const unsigned short* Kg = PatQK + ((size_t)g * 2 + 1) * 921600 + (size_t)split * klen * 144;
    const unsigned short* Vg = VT + (size_t)g * 921600 + split * klen;

    // Q fragments (B operand) pinned in registers
    short8 qf[9];
#pragma unroll
    for (int fs = 0; fs < 9; fs++)
        qf[fs] = *(const short8*)(Qg + (size_t)q * 144 + fs * 16 + h5 * 8);

    floatx16 O[5];
#pragma unroll
    for (int i = 0; i < 5; i++) O[i] = (floatx16)0.f;
    float m = -1e30f, lsum = 0.f;

    int koff = l31 * 144 + h5 * 8;              // K staging lane offset
    int vrow = (l31 > 15) ? 143 : 0;            // used for ft=4 clamp below
    int ra = (h5 * 32 + l31) * 8;               // fragment read offset (shorts)

    // stage tile 0 -> buf 0
    for (int c = w; c < 19; c += 4) {
        if (c < 9) gload16(Kg + koff + c * 16, &Ks[0][c * 512]);
        else {
            int cv = c - 9, ft = cv >> 1, ks = cv & 1;
            int f = ft * 32 + l31; if (f > 143) f = 143;
            gload16(Vg + (size_t)f * 6400 + ks * 16 + h5 * 8, &Vs[0][cv * 512]);
        }
    }

    for (int it = 0; it < niter; ++it) {
        int cb = it & 1;
        __syncthreads();   // drains async loads of tile it (vmcnt0) + barrier
        if (it + 1 < niter) {
            const unsigned short* Kt = Kg + (size_t)(it + 1) * 32 * 144;
            int vcol = (it + 1) * 32;
            int nb = cb ^ 1;
            for (int c = w; c < 19; c += 4) {
                if (c < 9) gload16(Kt + koff + c * 16, &Ks[nb][c * 512]);
                else {
                    int cv = c - 9, ft = cv >> 1, ks = cv & 1;
                    int f = ft * 32 + l31; if (f > 143) f = 143;
                    gload16(Vg + (size_t)f * 6400 + vcol + ks * 16 + h5 * 8, &Vs[nb][cv * 512]);
                }
            }
        }

        // S^T = K @ Q^T : one 32x32 C tile, 9 MFMA over f
        floatx16 S0 = (floatx16)0.f;
#pragma unroll
        for (int fs = 0; fs < 9; fs++) {
            short8 a0 = *(const short8*)&Ks[cb][fs * 512 + ra];
            S0 = __builtin_amdgcn_mfma_f32_32x32x16_bf16(a0, qf[fs], S0, 0, 0, 0);
        }

        // online softmax: lane's 16 scores belong to query col=l31
        float mt = -1e30f;
#pragma unroll
        for (int r = 0; r < 16; r++) mt = fmaxf(mt, S0[r]);
        mt = fmaxf(mt, __shfl_xor(mt, 32, 64));
        float mnew = fmaxf(m, mt);
        float alpha = exp2f(LOG2E10 * (m - mnew));
        float p[16], ps = 0.f;
#pragma unroll
        for (int r = 0; r < 16; r++) {
            p[r] = exp2f(LOG2E10 * (S0[r] - mnew));
            ps += p[r];
        }
        ps += __shfl_xor(ps, 32, 64);
        lsum = lsum * alpha + ps;
        m = mnew;
        if (__any(alpha < 1.f)) {
#pragma unroll
            for (int t5 = 0; t5 < 5; t5++)
#pragma unroll
                for (int r = 0; r < 16; r++) O[t5][r] *= alpha;
        }

        // pack P into bf16 pairs: W[a][c] covers keys (8a+4*h5+2c, +1)
        unsigned int W[4][2];
#pragma unroll
        for (int a = 0; a < 4; a++) {
            W[a][0] = pack2bf(p[4 * a + 0], p[4 * a + 1]);
            W[a][1] = pack2bf(p[4 * a + 2], p[4 * a + 3]);
        }

        // O^T += V^T @ P^T ; B-frag for chunk ks built via partner shuffle
#pragma unroll
        for (int ks = 0; ks < 2; ks++) {
            unsigned int s0 = h5 ? W[2 * ks][0] : W[2 * ks + 1][0];
            unsigned int s1 = h5 ? W[2 * ks][1] : W[2 * ks + 1][1];
            unsigned int r0 = (unsigned int)__shfl_xor((int)s0, 32, 64);
            unsigned int r1 = (unsigned int)__shfl_xor((int)s1, 32, 64);
            union { unsigned int u[4]; short8 s; } bw;
            if (!h5) { bw.u[0] = W[2 * ks][0]; bw.u[1] = W[2 * ks][1]; bw.u[2] = r0; bw.u[3] = r1; }
            else     { bw.u[0] = r0; bw.u[1] = r1; bw.u[2] = W[2 * ks + 1][0]; bw.u[3] = W[2 * ks + 1][1]; }
#pragma unroll
            for (int ft = 0; ft < 5; ft++) {
                short8 va = *(const short8*)&Vs[cb][(ft * 2 + ks) * 512 + ra];
                O[ft] = __builtin_amdgcn_mfma_f32_32x32x16_bf16(va, bw.s, O[ft], 0, 0, 0);
            }
        }
    }

    if (h5 == 0)
        ((float2*)ml)[((size_t)g * nsplit + split) * 6400 + q] = make_float2(m, lsum);

    unsigned short* Og = Opart + (((size_t)(g * nsplit + split)) * 6400 + q) * 144;
#pragma unroll
    for (int ft = 0; ft < 5; ft++)
#pragma unroll
        for (int rg = 0; rg < 4; rg++) {
            int f = ft * 32 + rg * 8 + h5 * 4;
            if (f < 144) {
                ushort4 st;
                st.x = f2bf(O[ft][4 * rg + 0]); st.y = f2bf(O[ft][4 * rg + 1]);
                st.z = f2bf(O[ft][4 * rg + 2]); st.w = f2bf(O[ft][4 * rg + 3]);
                *(ushort4*)(Og + f) = st;
            }
        }
    (void)vrow;
}

// ---------------- K3b: merge ksplit partials ----------------
__global__ void k_merge(const float* __restrict__ mlp, const unsigned short* __restrict__ Opart,
                        float* __restrict__ Zi, int nsplit) {
    int idx = blockIdx.x * 256 + threadIdx.x;  // 2*6400*36 exact
    int fg = idx % 36;
    int q = (idx / 36) % 6400;
    int g = idx / (36 * 6400);
    const float2* ml2 = (const float2*)mlp;
    float2 s[8];
    for (int k = 0; k < nsplit; k++) s[k] = ml2[((size_t)g * nsplit + k) * 6400 + q];
    float ms = s[0].x;
    for (int k = 1; k < nsplit; k++) ms = fmaxf(ms, s[k].x);
    float denom = 0.f, wgt[8];
    for (int k = 0; k < nsplit; k++) {
        wgt[k] = exp2f(LOG2E10 * (s[k].x - ms));
        denom += wgt[k] * s[k].y;
    }
    float inv = 1.f / denom;
    float a0 = 0.f, a1 = 0.f, a2 = 0.f, a3 = 0.f;
    for (int k = 0; k < nsplit; k++) {
        ushort4 u = *(const ushort4*)(Opart + (((size_t)(g * nsplit + k)) * 6400 + q) * 144 + fg * 4);
        a0 += wgt[k] * bf2f(u.x); a1 += wgt[k] * bf2f(u.y);
        a2 += wgt[k] * bf2f(u.z); a3 += wgt[k] * bf2f(u.w);
    }
    float4 out = make_float4(a0 * inv, a1 * inv, a2 * inv, a3 * inv);
    *(float4*)(Zi + ((size_t)g * 6400 + q) * 144 + fg * 4) = out;
}

// ---------------- K4: fold via scatter atomicAdd (zi2 pre-zeroed) ----------------
__global__ void k_scatter(const float* __restrict__ Zi, float* __restrict__ zi2) {
    int idx = blockIdx.x * 256 + threadIdx.x;  // 2*6400*144 = 7200*256 exact
    int f = idx % 144;
    int l = (idx / 144) % 6400;
    int g = idx / 921600;
    int ci = f / 9, kr = (f % 9) / 3, kc = f % 3;
    int oh = l / 80, ow = l % 80;
    int h = oh * 2 + kr - 1, w = ow * 2 + kc - 1;
    if (h >= 0 && h < 160 && w >= 0 && w < 160)
        atomicAdd(&zi2[(size_t)(g * 16 + ci) * NPIX + h * 160 + w], Zi[idx]);
}

// ---------------- K5: out = b + conv1x1(zi2/mask broadcast over D) ----------------
__global__ void k_final(const float* __restrict__ b, const float* __restrict__ zi2,
                        const float* __restrict__ Ww, const float* __restrict__ Wb,
                        float* __restrict__ out) {
    __shared__ float z[16 * 64];
    __shared__ float Wl[64 * 16];
    __shared__ float Bl[64];
    int tid = threadIdx.x;
    int g = blockIdx.y;
    int pxb = blockIdx.x * 64;
    for (int i = tid; i < 1024; i += 256) Wl[i] = Ww[i];
    if (tid < 64) Bl[tid] = Wb[tid];
    for (int i = tid; i < 1024; i += 256) {
        int ci = i >> 6, px = i & 63;
        int pix = pxb + px;
        int h = pix / 160, wp = pix % 160;
        float nh = (h & 1) ? ((h < 159) ? 2.f : 1.f) : 1.f;
        float nw = (wp & 1) ? ((wp < 159) ? 2.f : 1.f) : 1.f;
        z[i] = zi2[(size_t)(g * 16 + ci) * NPIX + pix] / (nh * nw);
    }
    __syncthreads();

    int px4 = tid & 15;
    int cg = tid >> 4;
    float acc[4][4];
#pragma unroll
    for (int c4 = 0; c4 < 4; c4++) {
        float bv = Bl[cg + 16 * c4];
#pragma unroll
        for (int j = 0; j < 4; j++) acc[c4][j] = bv;
    }
#pragma unroll
    for (int ci = 0; ci < 16; ci++) {
        float zv[4];
#pragma unroll
        for (int j = 0; j < 4; j++) zv[j] = z[ci * 64 + px4 * 4 + j];
#pragma unroll
        for (int c4 = 0; c4 < 4; c4++) {
            float wv = Wl[(cg + 16 * c4) * 16 + ci];
#pragma unroll
            for (int j = 0; j < 4; j++) acc[c4][j] += wv * zv[j];
        }
    }
    for (int d = 0; d < 8; d++) {
#pragma unroll
        for (int c4 = 0; c4 < 4; c4++) {
            int c = cg + 16 * c4;
            size_t base = ((size_t)(g * 64 + c) * 8 + d) * NPIX + pxb + px4 * 4;
            float4 bv = *(const float4*)(b + base);
            float4 ov = make_float4(bv.x + acc[c4][0], bv.y + acc[c4][1],
                                    bv.z + acc[c4][2], bv.w + acc[c4][3]);
            *(float4*)(out + base) = ov;
        }
    }
}

extern "C" void kernel_launch(void* const* d_in, const int* in_sizes, int n_in,
                              void* d_out, int out_size, void* d_ws, size_t ws_size,
                              hipStream_t stream) {
    const float* b   = (const float*)d_in[0];
    const float* gw  = (const float*)d_in[1];
    const float* gb  = (const float*)d_in[2];
    const float* thw = (const float*)d_in[3];
    const float* thb = (const float*)d_in[4];
    const float* phw = (const float*)d_in[5];
    const float* phb = (const float*)d_in[6];
    const float* Ww  = (const float*)d_in[7];
    const float* Wb  = (const float*)d_in[8];
    float* out = (float*)d_out;
    float* ws = (float*)d_ws;

    unsigned short* PatQK = (unsigned short*)ws;                 // 3,686,400 bf16
    unsigned short* VT    = (unsigned short*)(ws + 1843200);     // 1,843,200 bf16
    float*          ml    = ws + 2764800;                        //   204,800 f32 (ns=8 cap)
    unsigned short* P3    = (unsigned short*)(ws + 2969600);     // 2,457,600 bf16
    unsigned short* Opart = (unsigned short*)(ws + 2969600);     // overlays P3
    float*          Zi    = ws;                                  // overlays PatQK
    float*          zi2   = ws + 1843200;                        // overlays VT

    // ksplit=8 needs 41.4 MB workspace; fall back to proven 30.3 MB config
    int nsplit = (ws_size >= (size_t)10342400 * 4) ? 8 : 5;
    int klen = 6400 / nsplit;
    int niter = klen / 32;

    k_proj<<<dim3(100, 2), 256, 0, stream>>>(b, gw, gb, thw, thb, phw, phb, P3);
    k_unfold<<<dim3(21600), 256, 0, stream>>>(P3, PatQK, VT);
    k_attn<<<dim3(50, nsplit, 2), 256, 0, stream>>>(PatQK, VT, ml, Opart, nsplit, niter, klen);
    k_merge<<<dim3(1800), 256, 0, stream>>>(ml, Opart, Zi, nsplit);
    hipMemsetAsync(zi2, 0, (size_t)819200 * 4, stream);
    k_scatter<<<dim3(7200), 256, 0, stream>>>(Zi, zi2);
    k_final<<<dim3(400, 2), 256, 0, stream>>>(b, zi2, Ww, Wb, out);
}